// Round 5
// baseline (426.066 us; speedup 1.0000x reference)
//
#include <hip/hip_runtime.h>

#define VOCAB   32000
#define EMBED   2048
#define RANK    16
#define NADAPT  8
#define S_TOK   16384
#define T_TOK   256    // tokens per k2 block
#define GRP     8      // base-gather prefetch group
#define ECHUNK  256    // e-elements per block (1 per thread)

// ---------------- Kernel 1: bucket tokens by adapter ----------------
// d_ws layout: [0..7] int counters, [8 ..] int bucket[8][S_TOK]
__global__ __launch_bounds__(256)
void bucket_kernel(const int* __restrict__ input_ids,
                   const int* __restrict__ adapter_ids,
                   int* __restrict__ counters,
                   int* __restrict__ bucket)
{
    const int tid = threadIdx.x;
    const int t   = blockIdx.x * 256 + tid;
    int id = input_ids[t];
    if (id > VOCAB - 1) id = 0;
    const int ad = adapter_ids[t];

    __shared__ int hist[NADAPT];
    __shared__ int base[NADAPT];
    if (tid < NADAPT) hist[tid] = 0;
    __syncthreads();
    const int rank = atomicAdd(&hist[ad], 1);      // LDS atomic: local rank
    __syncthreads();
    if (tid < NADAPT)
        base[tid] = atomicAdd(&counters[tid], hist[tid]);  // global base
    __syncthreads();
    // pack: id < 2^15, t < 2^14  ->  (id<<16)|t fits in positive int32
    bucket[ad * S_TOK + base[ad] + rank] = (id << 16) | t;
}

// ---------------- Kernel 2: per-adapter fused embed + LoRA ----------------
__global__ __launch_bounds__(256, 4)
void lora_embed_kernel(const int* __restrict__ counters,
                       const int* __restrict__ bucket,
                       const float* __restrict__ weight,
                       const float* __restrict__ embA,
                       const float* __restrict__ embB,
                       float* __restrict__ out)
{
    const int tid    = threadIdx.x;
    const int echunk = blockIdx.x & 7;
    const int chunk  = (blockIdx.x >> 3) & 63;
    const int ad     = blockIdx.x >> 9;

    const int n     = counters[ad];
    const int start = chunk * T_TOK;
    if (start >= n) return;                 // over-dispatched block: no work
    const int cnt = min(T_TOK, n - start);
    const int e   = echunk * ECHUNK + tid;

    __shared__ int   pk_s[T_TOK];
    __shared__ float a_s[T_TOK][RANK];

    // stage packed (id, token) for this chunk
    if (tid < cnt) pk_s[tid] = bucket[ad * S_TOK + start + tid];
    __syncthreads();

    // stage LoRA-A vectors: cnt x 16 floats
    for (int j = tid; j < cnt * RANK; j += 256) {
        const int i = j >> 4, r = j & 15;
        const int id = ((unsigned)pk_s[i]) >> 16;
        a_s[i][r] = embA[((long)ad * VOCAB + id) * RANK + r];
    }

    // B slice for THIS adapter only: 16 VGPRs
    const float4* B4 = (const float4*)embB + ((long)ad * EMBED + e) * 4;
    const float4 b0 = B4[0], b1 = B4[1], b2 = B4[2], b3 = B4[3];
    __syncthreads();

    int g = 0;
    for (; g + GRP <= cnt; g += GRP) {
        float basev[GRP];
        int   idxg[GRP];
        #pragma unroll
        for (int u = 0; u < GRP; ++u) {
            const int pk = __builtin_amdgcn_readfirstlane(pk_s[g + u]);
            idxg[u] = pk & 0xFFFF;
            const int id = ((unsigned)pk) >> 16;
            basev[u] = weight[(long)id * EMBED + e];   // coalesced 4B/lane gather
        }
        #pragma unroll
        for (int u = 0; u < GRP; ++u) {
            const int i = g + u;
            const float4 a0 = *(const float4*)&a_s[i][0];
            const float4 a1 = *(const float4*)&a_s[i][4];
            const float4 a2 = *(const float4*)&a_s[i][8];
            const float4 a3 = *(const float4*)&a_s[i][12];
            float acc = basev[u];
            acc = fmaf(a0.x, b0.x, acc); acc = fmaf(a0.y, b0.y, acc);
            acc = fmaf(a0.z, b0.z, acc); acc = fmaf(a0.w, b0.w, acc);
            acc = fmaf(a1.x, b1.x, acc); acc = fmaf(a1.y, b1.y, acc);
            acc = fmaf(a1.z, b1.z, acc); acc = fmaf(a1.w, b1.w, acc);
            acc = fmaf(a2.x, b2.x, acc); acc = fmaf(a2.y, b2.y, acc);
            acc = fmaf(a2.z, b2.z, acc); acc = fmaf(a2.w, b2.w, acc);
            acc = fmaf(a3.x, b3.x, acc); acc = fmaf(a3.y, b3.y, acc);
            acc = fmaf(a3.z, b3.z, acc); acc = fmaf(a3.w, b3.w, acc);
            out[(long)idxg[u] * EMBED + e] = acc;
        }
    }
    // tail (partial group)
    for (; g < cnt; ++g) {
        const int pk = __builtin_amdgcn_readfirstlane(pk_s[g]);
        const int idx = pk & 0xFFFF;
        const int id  = ((unsigned)pk) >> 16;
        float acc = weight[(long)id * EMBED + e];
        const float4 a0 = *(const float4*)&a_s[g][0];
        const float4 a1 = *(const float4*)&a_s[g][4];
        const float4 a2 = *(const float4*)&a_s[g][8];
        const float4 a3 = *(const float4*)&a_s[g][12];
        acc = fmaf(a0.x, b0.x, acc); acc = fmaf(a0.y, b0.y, acc);
        acc = fmaf(a0.z, b0.z, acc); acc = fmaf(a0.w, b0.w, acc);
        acc = fmaf(a1.x, b1.x, acc); acc = fmaf(a1.y, b1.y, acc);
        acc = fmaf(a1.z, b1.z, acc); acc = fmaf(a1.w, b1.w, acc);
        acc = fmaf(a2.x, b2.x, acc); acc = fmaf(a2.y, b2.y, acc);
        acc = fmaf(a2.z, b2.z, acc); acc = fmaf(a2.w, b2.w, acc);
        acc = fmaf(a3.x, b3.x, acc); acc = fmaf(a3.y, b3.y, acc);
        acc = fmaf(a3.z, b3.z, acc); acc = fmaf(a3.w, b3.w, acc);
        out[(long)idx * EMBED + e] = acc;
    }
}

extern "C" void kernel_launch(void* const* d_in, const int* in_sizes, int n_in,
                              void* d_out, int out_size, void* d_ws, size_t ws_size,
                              hipStream_t stream) {
    const int*   input_ids   = (const int*)d_in[0];
    const int*   adapter_ids = (const int*)d_in[1];
    const float* weight      = (const float*)d_in[2];
    const float* embA        = (const float*)d_in[3];
    const float* embB        = (const float*)d_in[4];
    float*       out         = (float*)d_out;

    int* counters = (int*)d_ws;
    int* bucket   = counters + NADAPT;

    // zero the 8 bucket counters (ws is re-poisoned to 0xAA each call)
    hipMemsetAsync(counters, 0, NADAPT * sizeof(int), stream);

    hipLaunchKernelGGL(bucket_kernel, dim3(S_TOK / 256), dim3(256), 0, stream,
                       input_ids, adapter_ids, counters, bucket);

    // grid: 8 adapters x 64 token-chunks (worst case) x 8 e-chunks
    hipLaunchKernelGGL(lora_embed_kernel,
                       dim3(NADAPT * (S_TOK / T_TOK) * (EMBED / ECHUNK)), dim3(256),
                       0, stream,
                       counters, bucket, weight, embA, embB, out);
}

// Round 6
// 394.476 us; speedup vs baseline: 1.0801x; 1.0801x over previous
//
#include <hip/hip_runtime.h>

#define VOCAB   32000
#define EMBED   2048
#define RANK    16
#define NADAPT  8
#define S_TOK   16384
#define T_TOK   64     // tokens per k2 block (small => many active blocks => high TLP)
#define GRP     4      // base-gather prefetch group (4-deep MLP per wave)
#define ECHUNK  256    // e-elements per block (1 per thread)

// ---------------- Kernel 1: bucket tokens by adapter ----------------
// d_ws layout: [0..7] int counters, [8 ..] int bucket[8][S_TOK]
__global__ __launch_bounds__(256)
void bucket_kernel(const int* __restrict__ input_ids,
                   const int* __restrict__ adapter_ids,
                   int* __restrict__ counters,
                   int* __restrict__ bucket)
{
    const int tid = threadIdx.x;
    const int t   = blockIdx.x * 256 + tid;
    int id = input_ids[t];
    if (id > VOCAB - 1) id = 0;
    const int ad = adapter_ids[t];

    __shared__ int hist[NADAPT];
    __shared__ int base[NADAPT];
    if (tid < NADAPT) hist[tid] = 0;
    __syncthreads();
    const int rank = atomicAdd(&hist[ad], 1);      // LDS atomic: local rank
    __syncthreads();
    if (tid < NADAPT)
        base[tid] = atomicAdd(&counters[tid], hist[tid]);  // global base
    __syncthreads();
    // pack: id < 2^15, t < 2^14  ->  (id<<16)|t fits in positive int32
    bucket[ad * S_TOK + base[ad] + rank] = (id << 16) | t;
}

// ---------------- Kernel 2: per-adapter fused embed + LoRA ----------------
// occupancy goal: VGPR <= 64 -> 8 waves/SIMD; 2048 active blocks -> 8 blocks/CU
__global__ __launch_bounds__(256, 8)
void lora_embed_kernel(const int* __restrict__ counters,
                       const int* __restrict__ bucket,
                       const float* __restrict__ weight,
                       const float* __restrict__ embA,
                       const float* __restrict__ embB,
                       float* __restrict__ out)
{
    const int tid    = threadIdx.x;
    const int echunk = blockIdx.x & 7;                 // 8 e-chunks
    const int chunk  = (blockIdx.x >> 3) & 255;        // up to 256 token chunks
    const int ad     = blockIdx.x >> 11;               // 8 adapters

    const int n     = counters[ad];
    const int start = chunk * T_TOK;
    if (start >= n) return;                 // over-dispatched block: no work
    const int cnt = min(T_TOK, n - start);
    const int e   = echunk * ECHUNK + tid;

    __shared__ int   pk_s[T_TOK];
    __shared__ float a_s[T_TOK][RANK];

    // stage packed (id, token) for this chunk
    if (tid < cnt) pk_s[tid] = bucket[ad * S_TOK + start + tid];
    __syncthreads();

    // stage LoRA-A vectors: cnt x 16 floats (<= 4 KiB)
    for (int j = tid; j < cnt * RANK; j += 256) {
        const int i = j >> 4, r = j & 15;
        const int id = ((unsigned)pk_s[i]) >> 16;
        a_s[i][r] = embA[((long)ad * VOCAB + id) * RANK + r];
    }

    // B slice for THIS adapter only: 16 VGPRs
    const float4* B4 = (const float4*)embB + ((long)ad * EMBED + e) * 4;
    const float4 b0 = B4[0], b1 = B4[1], b2 = B4[2], b3 = B4[3];
    __syncthreads();

    int g = 0;
    for (; g + GRP <= cnt; g += GRP) {
        float basev[GRP];
        int   idxg[GRP];
        #pragma unroll
        for (int u = 0; u < GRP; ++u) {
            const int pk = __builtin_amdgcn_readfirstlane(pk_s[g + u]);   // SGPR
            idxg[u] = pk & 0xFFFF;
            const int id = ((unsigned)pk) >> 16;
            basev[u] = weight[(long)id * EMBED + e];   // coalesced 4B/lane gather
        }
        #pragma unroll
        for (int u = 0; u < GRP; ++u) {
            const int i = g + u;
            const float4 a0 = *(const float4*)&a_s[i][0];
            const float4 a1 = *(const float4*)&a_s[i][4];
            const float4 a2 = *(const float4*)&a_s[i][8];
            const float4 a3 = *(const float4*)&a_s[i][12];
            // 4 independent partial chains (shorter dependent-FMA chain)
            float s0 = a0.x*b0.x; s0 = fmaf(a0.y, b0.y, s0);
            s0 = fmaf(a0.z, b0.z, s0); s0 = fmaf(a0.w, b0.w, s0);
            float s1 = a1.x*b1.x; s1 = fmaf(a1.y, b1.y, s1);
            s1 = fmaf(a1.z, b1.z, s1); s1 = fmaf(a1.w, b1.w, s1);
            float s2 = a2.x*b2.x; s2 = fmaf(a2.y, b2.y, s2);
            s2 = fmaf(a2.z, b2.z, s2); s2 = fmaf(a2.w, b2.w, s2);
            float s3 = a3.x*b3.x; s3 = fmaf(a3.y, b3.y, s3);
            s3 = fmaf(a3.z, b3.z, s3); s3 = fmaf(a3.w, b3.w, s3);
            out[(long)idxg[u] * EMBED + e] = basev[u] + ((s0 + s1) + (s2 + s3));
        }
    }
    // tail (partial group)
    for (; g < cnt; ++g) {
        const int pk = __builtin_amdgcn_readfirstlane(pk_s[g]);
        const int idx = pk & 0xFFFF;
        const int id  = ((unsigned)pk) >> 16;
        const float basev = weight[(long)id * EMBED + e];
        const float4 a0 = *(const float4*)&a_s[g][0];
        const float4 a1 = *(const float4*)&a_s[g][4];
        const float4 a2 = *(const float4*)&a_s[g][8];
        const float4 a3 = *(const float4*)&a_s[g][12];
        float s0 = a0.x*b0.x; s0 = fmaf(a0.y, b0.y, s0);
        s0 = fmaf(a0.z, b0.z, s0); s0 = fmaf(a0.w, b0.w, s0);
        float s1 = a1.x*b1.x; s1 = fmaf(a1.y, b1.y, s1);
        s1 = fmaf(a1.z, b1.z, s1); s1 = fmaf(a1.w, b1.w, s1);
        float s2 = a2.x*b2.x; s2 = fmaf(a2.y, b2.y, s2);
        s2 = fmaf(a2.z, b2.z, s2); s2 = fmaf(a2.w, b2.w, s2);
        float s3 = a3.x*b3.x; s3 = fmaf(a3.y, b3.y, s3);
        s3 = fmaf(a3.z, b3.z, s3); s3 = fmaf(a3.w, b3.w, s3);
        out[(long)idx * EMBED + e] = basev + ((s0 + s1) + (s2 + s3));
    }
}

extern "C" void kernel_launch(void* const* d_in, const int* in_sizes, int n_in,
                              void* d_out, int out_size, void* d_ws, size_t ws_size,
                              hipStream_t stream) {
    const int*   input_ids   = (const int*)d_in[0];
    const int*   adapter_ids = (const int*)d_in[1];
    const float* weight      = (const float*)d_in[2];
    const float* embA        = (const float*)d_in[3];
    const float* embB        = (const float*)d_in[4];
    float*       out         = (float*)d_out;

    int* counters = (int*)d_ws;
    int* bucket   = counters + NADAPT;

    // zero the 8 bucket counters (ws is re-poisoned to 0xAA each call)
    hipMemsetAsync(counters, 0, NADAPT * sizeof(int), stream);

    hipLaunchKernelGGL(bucket_kernel, dim3(S_TOK / 256), dim3(256), 0, stream,
                       input_ids, adapter_ids, counters, bucket);

    // grid: 8 adapters x 256 token-chunks (worst case) x 8 e-chunks = 16384 blocks
    hipLaunchKernelGGL(lora_embed_kernel,
                       dim3(NADAPT * (S_TOK / T_TOK) * (EMBED / ECHUNK)), dim3(256),
                       0, stream,
                       counters, bucket, weight, embA, embB, out);
}